// Round 6
// baseline (349.296 us; speedup 1.0000x reference)
//
#include <hip/hip_runtime.h>

#define NH 16
#define DM 1024
#define SQ 2048
#define BT 4

typedef __attribute__((ext_vector_type(8))) short bf16x8;
typedef __attribute__((ext_vector_type(4))) short sh4;
typedef __attribute__((ext_vector_type(4))) float f4;
typedef __attribute__((ext_vector_type(4))) float fv4;
typedef unsigned short u16;
typedef unsigned int u32;

#define M2BIAS 23.083120654f   /* 16 * log2(e) */
#define SCALE2 0.18033688f     /* (1/8) * log2(e) */

__device__ __forceinline__ u16 f2bf(float f) {
    union { float f; unsigned u; } v; v.f = f;
    unsigned r = v.u + 0x7FFFu + ((v.u >> 16) & 1u);
    return (u16)(r >> 16);
}

__device__ __forceinline__ float fast_exp2(float x) {
#if __has_builtin(__builtin_amdgcn_exp2f)
    return __builtin_amdgcn_exp2f(x);
#else
    return exp2f(x);
#endif
}

// 16x16x16 bf16 MFMA: A[m=l16][k=quad*4+j]
#if __has_builtin(__builtin_amdgcn_mfma_f32_16x16x16_bf16)
#define MFMA16(a, b, c) __builtin_amdgcn_mfma_f32_16x16x16_bf16(a, b, c, 0, 0, 0)
#elif __has_builtin(__builtin_amdgcn_mfma_f32_16x16x16bf16_1k)
#define MFMA16(a, b, c) __builtin_amdgcn_mfma_f32_16x16x16bf16_1k(a, b, c, 0, 0, 0)
#else
static __device__ __forceinline__ f4 mfma16_asm(sh4 a, sh4 b, f4 c) {
    asm("v_mfma_f32_16x16x16_bf16 %0, %1, %2, %0" : "+v"(c) : "v"(a), "v"(b));
    return c;
}
#define MFMA16(a, b, c) mfma16_asm(a, b, c)
#endif

#define GLD16(gp, lp) __builtin_amdgcn_global_load_lds( \
    (const __attribute__((address_space(1))) void*)(gp), \
    (__attribute__((address_space(3))) void*)(lp), 16, 0, 0)

// pack 2 fp32 -> 2 truncated bf16 in one v_perm_b32 (used only for P in attn)
__device__ __forceinline__ u32 pk_trunc(float lo, float hi) {
    return __builtin_amdgcn_perm(__float_as_uint(hi), __float_as_uint(lo), 0x07060302u);
}
// pack 2 fp32 -> 2 ROUNDED bf16: bits+0x8000 (round half away, 0.5 ulp, unbiased-symmetric)
__device__ __forceinline__ u32 pk_round(float lo, float hi) {
    u32 a = __float_as_uint(lo) + 0x8000u;
    u32 b = __float_as_uint(hi) + 0x8000u;
    return __builtin_amdgcn_perm(b, a, 0x07060302u);
}

// ---------------- fp32 W[K][N] -> bf16 Wt[N][K], z-batched over 3 weights ----------------
__global__ __launch_bounds__(256) void cvt_wT(const float* __restrict__ W0, const float* __restrict__ W1,
                                              const float* __restrict__ W2, u16* __restrict__ Wt) {
    __shared__ float t[64][65];
    const float* Wsrc = blockIdx.z == 0 ? W0 : (blockIdx.z == 1 ? W1 : W2);
    u16* dst = Wt + (size_t)blockIdx.z * DM * DM;
    int r0 = blockIdx.x * 64, c0 = blockIdx.y * 64;
    #pragma unroll
    for (int i = 0; i < 16; ++i) {
        int idx = i * 256 + threadIdx.x;
        int r = idx >> 6, c = idx & 63;
        t[r][c] = Wsrc[(size_t)(r0 + r) * DM + c0 + c];
    }
    __syncthreads();
    #pragma unroll
    for (int i = 0; i < 16; ++i) {
        int idx = i * 256 + threadIdx.x;
        int n = idx >> 6, k = idx & 63;
        dst[(size_t)(c0 + n) * DM + r0 + k] = f2bf(t[k][n]);
    }
}

// ---------------- mask -> float bias (-M2 for keep, -inf for masked) ----------------
__global__ __launch_bounds__(256) void mk_mbias(const int* __restrict__ mask, float* __restrict__ mb) {
    int i = blockIdx.x * 256 + threadIdx.x;
    mb[i] = mask[i] ? -M2BIAS : -__builtin_inff();
}

// ---------------- fused projection GEMM (z = 0:Q, 1:K, 2:V) ----------------
// A fp32 [8192,1024] staged raw into LDS (global_load_lds, 16B-chunk XOR swizzle),
// converted to bf16 on LDS->reg read (rounded, pk_round). Bt bf16 [N,K].
// z<2: compute C^T (swap MFMA operands) -> packed b64 stores along d into [B,H,S,64].
// z=2: compute C -> packed b64 stores along s into v^T [B,H,64,S].
__global__ __launch_bounds__(256) void gemm_fused(const float* __restrict__ Xq, const float* __restrict__ Xk,
                                                  const float* __restrict__ Xv, const u16* __restrict__ Wt,
                                                  const float* __restrict__ bqv, const float* __restrict__ bkv,
                                                  const float* __restrict__ bvv,
                                                  u16* __restrict__ qo, u16* __restrict__ ko, u16* __restrict__ vo) {
    __shared__ float Asf[128 * 64];  // 32 KB
    __shared__ u16 Bs[128 * 64];     // 16 KB
    int z = blockIdx.z;
    const float* A    = z == 0 ? Xq : (z == 1 ? Xk : Xv);
    const float* bias = z == 0 ? bqv : (z == 1 ? bkv : bvv);
    u16* outp         = z == 0 ? qo : (z == 1 ? ko : vo);
    const u16* Bg = Wt + (size_t)z * DM * DM + (size_t)blockIdx.y * 128 * DM;
    const float* Ag = A + (size_t)blockIdx.x * 128 * DM;
    bool vt = (z == 2);

    int tid = threadIdx.x;
    int w = tid >> 6, lane = tid & 63, quad = lane >> 4, l16 = lane & 15;
    int wm = w >> 1, wn = w & 1;
    int r8 = lane >> 3, cg = (lane & 7) ^ r8;   // B staging swizzle (8-elem chunks)
    int l4 = lane >> 4, s16 = lane & 15;        // A staging: row-in-group, slot

    f4 acc[4][4];
    #pragma unroll
    for (int i = 0; i < 4; ++i)
        #pragma unroll
        for (int j = 0; j < 4; ++j) acc[i][j] = f4{0.f, 0.f, 0.f, 0.f};

    // A-read swizzle (loop-invariant): fragment rows have row&15 == l16
    int aswz = ((l16 & 7) << 1) | (l16 >> 3);

    for (int kt = 0; kt < 16; ++kt) {
        // stage A fp32: 8 instrs/wave, each 4 rows x 256B
        #pragma unroll
        for (int c = 0; c < 8; ++c) {
            int rl = w * 32 + c * 4 + l4;
            int rm = rl & 15;
            int g = s16 ^ (((rm & 7) << 1) | (rm >> 3));
            GLD16(Ag + (size_t)rl * DM + kt * 64 + g * 4, &Asf[(w * 32 + c * 4) * 64]);
        }
        // stage B bf16: 4 instrs/wave
        #pragma unroll
        for (int c = 0; c < 4; ++c) {
            int rbase = w * 32 + c * 8;
            GLD16(Bg + (size_t)(rbase + r8) * DM + kt * 64 + cg * 8, &Bs[rbase * 64]);
        }
        __syncthreads();
        #pragma unroll
        for (int ks = 0; ks < 2; ++ks) {
            bf16x8 afr[4], bfr[4];
            #pragma unroll
            for (int mt = 0; mt < 4; ++mt) {
                int row = wm * 64 + mt * 16 + l16;
                int s0 = (ks * 8 + quad * 2) ^ aswz;
                f4 a0 = *(const f4*)&Asf[row * 64 + s0 * 4];
                f4 a1 = *(const f4*)&Asf[row * 64 + (s0 ^ 1) * 4];
                union { bf16x8 v; u32 u[4]; } af;
                af.u[0] = pk_round(a0[0], a0[1]);
                af.u[1] = pk_round(a0[2], a0[3]);
                af.u[2] = pk_round(a1[0], a1[1]);
                af.u[3] = pk_round(a1[2], a1[3]);
                afr[mt] = af.v;
            }
            #pragma unroll
            for (int nt = 0; nt < 4; ++nt) {
                int row = wn * 64 + nt * 16 + l16;
                int ch = (ks * 4 + quad) ^ (row & 7);
                bfr[nt] = *(const bf16x8*)&Bs[row * 64 + ch * 8];
            }
            #pragma unroll
            for (int i = 0; i < 4; ++i)
                #pragma unroll
                for (int j = 0; j < 4; ++j)
                    acc[i][j] = __builtin_amdgcn_mfma_f32_16x16x32_bf16(
                        vt ? afr[i] : bfr[i], vt ? bfr[j] : afr[j], acc[i][j], 0, 0, 0);
        }
        __syncthreads();
    }

    if (!vt) {
        // acc[nt][mt] = C^T tile: lane l16 = s-row, quad*4+reg = d-col
        #pragma unroll
        for (int nt = 0; nt < 4; ++nt) {
            int ncb = blockIdx.y * 128 + wn * 64 + nt * 16 + quad * 4;
            fv4 bn4 = *(const fv4*)&bias[ncb];
            int h = ncb >> 6, d0 = ncb & 63;
            #pragma unroll
            for (int mt = 0; mt < 4; ++mt) {
                int s = blockIdx.x * 128 + wm * 64 + mt * 16 + l16;
                int bidx = s >> 11, srow = s & 2047;
                sh4 pk;
                #pragma unroll
                for (int reg = 0; reg < 4; ++reg) pk[reg] = (short)f2bf(acc[nt][mt][reg] + bn4[reg]);
                *(sh4*)&outp[(((size_t)bidx * NH + h) * SQ + srow) * 64 + d0] = pk;
            }
        }
    } else {
        // acc[mt][nt] = C tile: lane l16 = d-col, quad*4+reg = s-row
        #pragma unroll
        for (int nt = 0; nt < 4; ++nt) {
            int ncol = blockIdx.y * 128 + wn * 64 + nt * 16 + l16;
            float bn = bias[ncol];
            int h = ncol >> 6, d = ncol & 63;
            #pragma unroll
            for (int mt = 0; mt < 4; ++mt) {
                int mbase = blockIdx.x * 128 + wm * 64 + mt * 16 + quad * 4;
                int bidx = mbase >> 11, s0 = mbase & 2047;
                sh4 pk;
                #pragma unroll
                for (int reg = 0; reg < 4; ++reg) pk[reg] = (short)f2bf(acc[mt][nt][reg] + bn);
                *(sh4*)&outp[(((size_t)bidx * NH + h) * 64 + d) * SQ + s0] = pk;
            }
        }
    }
}

// ---------------- flash attention (S^T form, register-resident P) ----------------
__global__ __launch_bounds__(256, 4) void attn(const u16* __restrict__ qw, const u16* __restrict__ kw,
                                               const u16* __restrict__ vtw, const float* __restrict__ mbias,
                                               float* __restrict__ outp) {
    __shared__ u16 Ks[2][64 * 64];
    __shared__ u16 Vs[2][64 * 64];
    int tid = threadIdx.x;
    int w = tid >> 6, lane = tid & 63, quad = lane >> 4, l16 = lane & 15;
    int r8 = lane >> 3, sl = lane & 7;
    int bh = blockIdx.x, b = bh >> 4;
    int h = bh & 15;
    int qbase = blockIdx.y * 128 + w * 32;
    const u16* qp = qw + (size_t)bh * SQ * 64;
    const u16* kp = kw + (size_t)bh * SQ * 64;
    const u16* vp = vtw + (size_t)bh * 64 * SQ;
    const float* mbq = mbias + b * SQ + quad * 4;

    bf16x8 aq[2][2];
    #pragma unroll
    for (int mt = 0; mt < 2; ++mt)
        #pragma unroll
        for (int ks = 0; ks < 2; ++ks)
            aq[mt][ks] = *(const bf16x8*)&qp[(size_t)(qbase + mt * 16 + l16) * 64 + ks * 32 + quad * 8];

    // ---- loop-invariant LDS offsets (u16 indices) ----
    int bk_off[4][2], bv_off[4][4];
    #pragma unroll
    for (int kt = 0; kt < 4; ++kt) {
        int r = kt * 16 + l16;
        #pragma unroll
        for (int ks = 0; ks < 2; ++ks)
            bk_off[kt][ks] = r * 64 + (((ks * 4 + quad) ^ (l16 & 7)) * 8);
        #pragma unroll
        for (int nt = 0; nt < 4; ++nt) {
            int row = nt * 16 + l16;
            int ch = (2 * kt + (quad >> 1)) ^ (l16 & 7);
            bv_off[kt][nt] = row * 64 + ch * 8 + (quad & 1) * 4;
        }
    }
    // staging addresses (gsl invariant: row&7 == r8)
    int gsl = sl ^ r8;
    int krow0 = w * 16 + r8, krow1 = krow0 + 8;
    const u16* kp0 = kp + (size_t)krow0 * 64 + gsl * 8;
    const u16* kp1 = kp + (size_t)krow1 * 64 + gsl * 8;
    const u16* vp0 = vp + (size_t)krow0 * SQ + gsl * 8;
    const u16* vp1 = vp + (size_t)krow1 * SQ + gsl * 8;
    u16* KsW0 = &Ks[0][(w * 16) * 64];       u16* KsW0b = &Ks[0][(w * 16 + 8) * 64];
    u16* VsW0 = &Vs[0][(w * 16) * 64];       u16* VsW0b = &Vs[0][(w * 16 + 8) * 64];
    u16* KsW1 = &Ks[1][(w * 16) * 64];       u16* KsW1b = &Ks[1][(w * 16 + 8) * 64];
    u16* VsW1 = &Vs[1][(w * 16) * 64];       u16* VsW1b = &Vs[1][(w * 16 + 8) * 64];

    f4 o[2][4];
    float lrow[2] = {0.f, 0.f};
    #pragma unroll
    for (int mt = 0; mt < 2; ++mt)
        #pragma unroll
        for (int nt = 0; nt < 4; ++nt) o[mt][nt] = f4{0.f, 0.f, 0.f, 0.f};

    // prologue stage into buf 0
    GLD16(kp0, KsW0); GLD16(kp1, KsW0b);
    GLD16(vp0, VsW0); GLD16(vp1, VsW0b);

    #pragma unroll 2
    for (int kb = 0; kb < 32; ++kb) {
        int buf = kb & 1;
        int k0 = kb * 64;
        __syncthreads();
        fv4 bias4[4];
        #pragma unroll
        for (int kt = 0; kt < 4; ++kt)
            bias4[kt] = *(const fv4*)&mbq[k0 + kt * 16];
        if (kb + 1 < 32) {
            int kn = k0 + 64;
            if (buf == 0) {
                GLD16(kp0 + kn * 64, KsW1); GLD16(kp1 + kn * 64, KsW1b);
                GLD16(vp0 + kn, VsW1);      GLD16(vp1 + kn, VsW1b);
            } else {
                GLD16(kp0 + kn * 64, KsW0); GLD16(kp1 + kn * 64, KsW0b);
                GLD16(vp0 + kn, VsW0);      GLD16(vp1 + kn, VsW0b);
            }
        }

        const u16* Kb = Ks[buf];
        const u16* Vb = Vs[buf];
        bf16x8 bk[4][2];
        #pragma unroll
        for (int kt = 0; kt < 4; ++kt)
            #pragma unroll
            for (int ks = 0; ks < 2; ++ks)
                bk[kt][ks] = *(const bf16x8*)&Kb[bk_off[kt][ks]];
        f4 S[4][2];
        #pragma unroll
        for (int kt = 0; kt < 4; ++kt)
            #pragma unroll
            for (int mt = 0; mt < 2; ++mt) {
                f4 s = f4{0.f, 0.f, 0.f, 0.f};
                s = __builtin_amdgcn_mfma_f32_16x16x32_bf16(bk[kt][0], aq[mt][0], s, 0, 0, 0);
                s = __builtin_amdgcn_mfma_f32_16x16x32_bf16(bk[kt][1], aq[mt][1], s, 0, 0, 0);
                S[kt][mt] = s;
            }
        #pragma unroll
        for (int kt = 0; kt < 4; ++kt) {
            sh4 pa[2];
            #pragma unroll
            for (int mt = 0; mt < 2; ++mt) {
                f4 s = S[kt][mt];
                float p0 = fast_exp2(s[0] * SCALE2 + bias4[kt][0]);
                float p1 = fast_exp2(s[1] * SCALE2 + bias4[kt][1]);
                float p2 = fast_exp2(s[2] * SCALE2 + bias4[kt][2]);
                float p3 = fast_exp2(s[3] * SCALE2 + bias4[kt][3]);
                lrow[mt] += (p0 + p1) + (p2 + p3);
                union { sh4 v; u32 u[2]; } pk;
                pk.u[0] = pk_trunc(p0, p1);
                pk.u[1] = pk_trunc(p2, p3);
                pa[mt] = pk.v;
            }
            sh4 bv[4];
            #pragma unroll
            for (int nt = 0; nt < 4; ++nt)
                bv[nt] = *(const sh4*)&Vb[bv_off[kt][nt]];
            #pragma unroll
            for (int mt = 0; mt < 2; ++mt)
                #pragma unroll
                for (int nt = 0; nt < 4; ++nt)
                    o[mt][nt] = MFMA16(pa[mt], bv[nt], o[mt][nt]);
        }
    }

    #pragma unroll
    for (int mt = 0; mt < 2; ++mt) {
        float v = lrow[mt];
        v += __shfl_xor(v, 16);
        v += __shfl_xor(v, 32);
        #pragma unroll
        for (int reg = 0; reg < 4; ++reg) {
            float inv = 1.f / __shfl(v, quad * 4 + reg);
            int row = qbase + mt * 16 + quad * 4 + reg;
            size_t obase = ((size_t)b * SQ + row) * DM + h * 64;
            #pragma unroll
            for (int nt = 0; nt < 4; ++nt)
                outp[obase + nt * 16 + l16] = o[mt][nt][reg] * inv;
        }
    }
}

extern "C" void kernel_launch(void* const* d_in, const int* in_sizes, int n_in,
                              void* d_out, int out_size, void* d_ws, size_t ws_size,
                              hipStream_t stream) {
    (void)in_sizes; (void)n_in; (void)out_size; (void)ws_size;
    const float* Q  = (const float*)d_in[0];
    const float* K  = (const float*)d_in[1];
    const float* V  = (const float*)d_in[2];
    const int* mask = (const int*)d_in[3];
    const float* Wq = (const float*)d_in[4];
    const float* bq = (const float*)d_in[5];
    const float* Wk = (const float*)d_in[6];
    const float* bk = (const float*)d_in[7];
    const float* Wv = (const float*)d_in[8];
    const float* bv = (const float*)d_in[9];
    float* out = (float*)d_out;
    char* ws = (char*)d_ws;
    // ws layout (~54.2 MB): q 16MB | k 16MB | v^T 16MB | wbuf 6MB | mb 32KB
    u16* q_ws = (u16*)(ws);
    u16* k_ws = (u16*)(ws + (size_t)16 * 1024 * 1024);
    u16* v_ws = (u16*)(ws + (size_t)32 * 1024 * 1024);
    u16* wbuf = (u16*)(ws + (size_t)48 * 1024 * 1024);
    float* mb = (float*)(ws + (size_t)54 * 1024 * 1024);

    cvt_wT<<<dim3(16, 16, 3), 256, 0, stream>>>(Wq, Wk, Wv, wbuf);
    mk_mbias<<<32, 256, 0, stream>>>(mask, mb);
    gemm_fused<<<dim3(64, 8, 3), 256, 0, stream>>>(Q, K, V, wbuf, bq, bk, bv, q_ws, k_ws, v_ws);
    attn<<<dim3(64, 16), 256, 0, stream>>>(q_ws, k_ws, v_ws, mb, out);
}